// Round 3
// baseline (191.606 us; speedup 1.0000x reference)
//
#include <hip/hip_runtime.h>

// Problem constants (match reference)
namespace {
constexpr int Bc     = 4;
constexpr int Nc     = 16384;
constexpr int Kc     = 27;        // 3^3
constexpr int SHIFTc = 3;
constexpr int BASEc  = 70;        // CMAX + 2*KS
constexpr int BASE3c = BASEc * BASEc * BASEc;   // 343000
constexpr int TABLEc = Bc * BASE3c;             // 1,372,000 dense key space
constexpr int NKc    = Nc * Kc;                 // 442,368
constexpr int Tc     = Bc * NKc;                // 1,769,472
constexpr int SBLOCK = 256;
constexpr int SITEMS = 8;
constexpr int SCHUNK = SBLOCK * SITEMS;         // 2048
constexpr int NBLK   = Tc / SCHUNK;             // 864 (exact)
constexpr int NTHREADS = NBLK * SBLOCK;         // 221,184
constexpr int INTMAXv = 0x7fffffff;
}

// K1: init first[] = INT_MAX; write in_idx / rel_pos (int4 stores)
__global__ void __launch_bounds__(SBLOCK)
k1_init(int* __restrict__ first, int* __restrict__ in_idx,
        int* __restrict__ rel_pos) {
    const int g = blockIdx.x * blockDim.x + threadIdx.x;
    const int stride = gridDim.x * blockDim.x;
    const int4 iv = make_int4(INTMAXv, INTMAXv, INTMAXv, INTMAXv);
    const int n4 = TABLEc / 4;                 // 343,000 (exact)
    for (int i = g; i < n4; i += stride)
        reinterpret_cast<int4*>(first)[i] = iv;
    const int t4 = Tc / 4;                     // 442,368 (exact)
    for (int i = g; i < t4; i += stride) {
        int t = 4 * i;
        int4 a, r;
        a.x = (t / Kc) % Nc;       r.x = t % Kc;
        a.y = ((t + 1) / Kc) % Nc; r.y = (t + 1) % Kc;
        a.z = ((t + 2) / Kc) % Nc; r.z = (t + 2) % Kc;
        a.w = ((t + 3) / Kc) % Nc; r.w = (t + 3) % Kc;
        reinterpret_cast<int4*>(in_idx)[i]  = a;
        reinterpret_cast<int4*>(rel_pos)[i] = r;
    }
}

// K2: compute keys ONCE (store coalesced), atomicMin first[key] = t
__global__ void __launch_bounds__(SBLOCK)
k2_keys(const int* __restrict__ coords, const int* __restrict__ batch,
        int* __restrict__ first, int* __restrict__ keys) {
    const int tid = threadIdx.x, bid = blockIdx.x;
    const int t0 = bid * SCHUNK + tid * SITEMS;
    int kv[SITEMS];
    #pragma unroll
    for (int i = 0; i < SITEMS; ++i) {
        int t  = t0 + i;
        int pt = t / Kc;              // b*N + idx
        int k  = t - pt * Kc;
        int cb = pt * 3;
        int x = coords[cb], y = coords[cb + 1], z = coords[cb + 2];
        int dx = k / 9 - 1;
        int dy = (k / 3) % 3 - 1;
        int dz = k - (k / 3) * 3 - 1;
        int bb = batch[pt];
        kv[i] = bb * BASE3c
              + ((x + dx + SHIFTc) * BASEc + (y + dy + SHIFTc)) * BASEc
              + (z + dz + SHIFTc);
        atomicMin(&first[kv[i]], t);
    }
    int4* kd = reinterpret_cast<int4*>(keys + t0);
    kd[0] = make_int4(kv[0], kv[1], kv[2], kv[3]);
    kd[1] = make_int4(kv[4], kv[5], kv[6], kv[7]);
}

// K3: predicate bits per thread + per-block sums
__global__ void __launch_bounds__(SBLOCK)
k3_pred(const int* __restrict__ keys, const int* __restrict__ first,
        int* __restrict__ predbits_arr, int* __restrict__ blockSums) {
    __shared__ int sdata[SBLOCK];
    const int tid = threadIdx.x, bid = blockIdx.x;
    const int t0 = bid * SCHUNK + tid * SITEMS;
    const int4* kd = reinterpret_cast<const int4*>(keys + t0);
    int4 ka = kd[0], kb = kd[1];
    const int kv[SITEMS] = {ka.x, ka.y, ka.z, ka.w, kb.x, kb.y, kb.z, kb.w};
    int pb = 0, ps = 0;
    #pragma unroll
    for (int i = 0; i < SITEMS; ++i) {
        int p = (first[kv[i]] == t0 + i) ? 1 : 0;
        pb |= p << i;
        ps += p;
    }
    predbits_arr[bid * SBLOCK + tid] = pb;
    sdata[tid] = ps;
    __syncthreads();
    for (int off = SBLOCK / 2; off > 0; off >>= 1) {
        if (tid < off) sdata[tid] += sdata[tid + off];
        __syncthreads();
    }
    if (tid == 0) blockSums[bid] = sdata[0];
}

// K5: every block reduces blockSums itself (sum_before_bid + total),
//     LDS scan of per-thread popcounts, scatter ranks + out_key, tail fill
__global__ void __launch_bounds__(SBLOCK)
k5_scatter(const int* __restrict__ keys, const int* __restrict__ predbits_arr,
           const int* __restrict__ blockSums, int* __restrict__ rank_table,
           int* __restrict__ out_key, int* __restrict__ num_out) {
    __shared__ unsigned long long pdata[SBLOCK];
    __shared__ int sdata[SBLOCK];
    const int tid = threadIdx.x, bid = blockIdx.x;
    const int t0 = bid * SCHUNK + tid * SITEMS;

    // packed reduction: hi32 = total, lo32 = sum over j < bid
    unsigned long long acc = 0;
    for (int j = tid; j < NBLK; j += SBLOCK) {
        unsigned long long v = (unsigned)blockSums[j];
        acc += (v << 32) | (j < bid ? v : 0ull);
    }
    pdata[tid] = acc;
    __syncthreads();
    for (int off = SBLOCK / 2; off > 0; off >>= 1) {
        if (tid < off) pdata[tid] += pdata[tid + off];
        __syncthreads();
    }
    const int num    = (int)(pdata[0] >> 32);
    const int before = (int)(pdata[0] & 0xffffffffull);

    // block-local exclusive base from predbits
    const int pb = predbits_arr[bid * SBLOCK + tid];
    const int ps = __popc(pb);
    sdata[tid] = ps;
    __syncthreads();
    #pragma unroll
    for (int off = 1; off < SBLOCK; off <<= 1) {
        int u = (tid >= off) ? sdata[tid - off] : 0;
        __syncthreads();
        sdata[tid] += u;
        __syncthreads();
    }
    int r = before + (sdata[tid] - ps);

    const int4* kd = reinterpret_cast<const int4*>(keys + t0);
    int4 ka = kd[0], kb = kd[1];
    const int kv[SITEMS] = {ka.x, ka.y, ka.z, ka.w, kb.x, kb.y, kb.z, kb.w};
    #pragma unroll
    for (int i = 0; i < SITEMS; ++i) {
        int t = t0 + i;
        if ((pb >> i) & 1) {
            rank_table[kv[i]] = r;
            int rem = kv[i] % BASE3c;
            int x = rem / (BASEc * BASEc) - SHIFTc;
            int y = (rem / BASEc) % BASEc - SHIFTc;
            int z = rem % BASEc - SHIFTc;
            out_key[3 * r + 0] = x;
            out_key[3 * r + 1] = y;
            out_key[3 * r + 2] = z;
            ++r;
        }
        if (t >= num) {
            out_key[3 * t + 0] = -1;
            out_key[3 * t + 1] = -1;
            out_key[3 * t + 2] = -1;
        }
    }
    if (bid == 0 && tid == 0) num_out[0] = num;
}

// K6: out_idx[t] = rank_table[keys[t]]  (int4 loads/stores)
__global__ void __launch_bounds__(SBLOCK)
k6_outidx(const int* __restrict__ keys, const int* __restrict__ rank_table,
          int* __restrict__ out_idx) {
    const int tid = threadIdx.x, bid = blockIdx.x;
    const int t0 = bid * SCHUNK + tid * SITEMS;
    const int4* kd = reinterpret_cast<const int4*>(keys + t0);
    int4 ka = kd[0], kb = kd[1];
    const int kv[SITEMS] = {ka.x, ka.y, ka.z, ka.w, kb.x, kb.y, kb.z, kb.w};
    int vals[SITEMS];
    #pragma unroll
    for (int i = 0; i < SITEMS; ++i) vals[i] = rank_table[kv[i]];
    int4* o4 = reinterpret_cast<int4*>(out_idx + t0);
    o4[0] = make_int4(vals[0], vals[1], vals[2], vals[3]);
    o4[1] = make_int4(vals[4], vals[5], vals[6], vals[7]);
}

extern "C" void kernel_launch(void* const* d_in, const int* in_sizes, int n_in,
                              void* d_out, int out_size, void* d_ws, size_t ws_size,
                              hipStream_t stream) {
    const int* coords = (const int*)d_in[0];   // [B, N, 3]
    const int* batch  = (const int*)d_in[1];   // [B, N]
    int* out = (int*)d_out;
    int* in_idx  = out;                 // [T]
    int* out_idx = out + Tc;            // [T]
    int* rel_pos = out + 2 * Tc;        // [T]
    int* out_key = out + 3 * Tc;        // [T,3]
    int* num_out = out + 6 * Tc;        // [1]

    int* ws = (int*)d_ws;
    int* first       = ws;                        // TABLEc
    int* rank_table  = ws + TABLEc;               // TABLEc
    int* keys        = ws + 2 * TABLEc;           // Tc (32B aligned: offsets even)
    int* predbits    = keys + Tc;                 // NTHREADS
    int* blockSums   = predbits + NTHREADS;       // NBLK

    k1_init<<<1024, SBLOCK, 0, stream>>>(first, in_idx, rel_pos);
    k2_keys<<<NBLK, SBLOCK, 0, stream>>>(coords, batch, first, keys);
    k3_pred<<<NBLK, SBLOCK, 0, stream>>>(keys, first, predbits, blockSums);
    k5_scatter<<<NBLK, SBLOCK, 0, stream>>>(keys, predbits, blockSums,
                                            rank_table, out_key, num_out);
    k6_outidx<<<NBLK, SBLOCK, 0, stream>>>(keys, rank_table, out_idx);
}

// Round 4
// 125.903 us; speedup vs baseline: 1.5218x; 1.5218x over previous
//
#include <hip/hip_runtime.h>

// Problem constants (match reference)
namespace {
constexpr int Bc   = 4;
constexpr int Nc   = 16384;
constexpr int Kc   = 27;
constexpr int Pc   = 68;                    // padded cells per axis: coords -2..65
constexpr int P2c  = Pc * Pc;               // 4624
constexpr int P3c  = Pc * P2c;              // 314432 cells per batch (padded)
constexpr int NPts = Bc * Nc;               // 65536
constexpr int Tc   = NPts * Kc;             // 1,769,472
constexpr int INFv = 0x7fffffff;
constexpr int PBLK = 256;                   // points per block
constexpr int NPB  = NPts / PBLK;           // 256 blocks (exact)
}

__device__ __forceinline__ int min3i(int a, int b, int c) {
    return min(min(a, b), c);
}
// cell index with +2 halo fold: pass raw coords in [-2, 65]
__device__ __forceinline__ int cid(int bb, int x, int y, int z) {
    return bb * P3c + ((x + 2) * Pc + (y + 2)) * Pc + (z + 2);
}

// K1: init padded cell_min table to INT_MAX
__global__ void __launch_bounds__(256)
k1_init(int* __restrict__ cell_min) {
    const int g = blockIdx.x * blockDim.x + threadIdx.x;
    const int stride = gridDim.x * blockDim.x;
    const int n4 = (Bc * P3c) / 4;          // 314,432 int4 (exact)
    const int4 iv = make_int4(INFv, INFv, INFv, INFv);
    for (int i = g; i < n4; i += stride)
        reinterpret_cast<int4*>(cell_min)[i] = iv;
}

// K2: one atomicMin per POINT (65,536 total)
__global__ void __launch_bounds__(256)
k2_cellmin(const int* __restrict__ coords, const int* __restrict__ batch,
           int* __restrict__ cell_min) {
    const int pt = blockIdx.x * blockDim.x + threadIdx.x;
    if (pt >= NPts) return;
    const int idx = pt & (Nc - 1);
    const int bb  = batch[pt];
    const int x = coords[3 * pt], y = coords[3 * pt + 1], z = coords[3 * pt + 2];
    atomicMin(&cell_min[cid(bb, x, y, z)], idx);
}

// K3: per-point separable 5x5x5 sliding window min -> 27 first-occurrence
//     predicate bits; per-block popcount sums
__global__ void __launch_bounds__(PBLK)
k3_pred(const int* __restrict__ coords, const int* __restrict__ batch,
        const int* __restrict__ cell_min,
        int* __restrict__ predbits, int* __restrict__ blockSums) {
    __shared__ int sdata[PBLK];
    const int tid = threadIdx.x, bid = blockIdx.x;
    const int pt  = bid * PBLK + tid;
    const int idx = pt & (Nc - 1);
    const int bb  = batch[pt];
    const int x = coords[3 * pt], y = coords[3 * pt + 1], z = coords[3 * pt + 2];
    // base = cid(bb, x-2, y-2, z-2)
    const int base = bb * P3c + (x * Pc + y) * Pc + z;

    int p9[5][9];   // per x-plane, yz-window mins
    #pragma unroll
    for (int xi = 0; xi < 5; ++xi) {
        const int* plane = cell_min + base + xi * P2c;
        int mz[5][3];
        #pragma unroll
        for (int yj = 0; yj < 5; ++yj) {
            const int* q = plane + yj * Pc;
            int v0 = q[0], v1 = q[1], v2 = q[2], v3 = q[3], v4 = q[4];
            mz[yj][0] = min3i(v0, v1, v2);
            mz[yj][1] = min3i(v1, v2, v3);
            mz[yj][2] = min3i(v2, v3, v4);
        }
        #pragma unroll
        for (int sy = 0; sy < 3; ++sy)
            #pragma unroll
            for (int sz = 0; sz < 3; ++sz)
                p9[xi][sy * 3 + sz] =
                    min3i(mz[sy][sz], mz[sy + 1][sz], mz[sy + 2][sz]);
    }
    int pb = 0;
    #pragma unroll
    for (int sx = 0; sx < 3; ++sx)
        #pragma unroll
        for (int j = 0; j < 9; ++j) {
            int m = min3i(p9[sx][j], p9[sx + 1][j], p9[sx + 2][j]);
            pb |= (m == idx) ? (1 << (sx * 9 + j)) : 0;
        }
    predbits[pt] = pb;

    sdata[tid] = __popc(pb);
    __syncthreads();
    for (int off = PBLK / 2; off > 0; off >>= 1) {
        if (tid < off) sdata[tid] += sdata[tid + off];
        __syncthreads();
    }
    if (tid == 0) blockSums[bid] = sdata[0];
}

// K4: rank scan + scatter rank_table / out_key, tail fill, num_out
__global__ void __launch_bounds__(PBLK)
k4_scatter(const int* __restrict__ coords, const int* __restrict__ batch,
           const int* __restrict__ predbits, const int* __restrict__ blockSums,
           int* __restrict__ rank_table, int* __restrict__ out_key,
           int* __restrict__ num_out) {
    __shared__ int sdata[PBLK];
    const int tid = threadIdx.x, bid = blockIdx.x;
    const int pt  = bid * PBLK + tid;

    // scan the 256 block sums (every block does it; 1 KB of L2 reads)
    int bs = blockSums[tid];            // NPB == PBLK == 256
    sdata[tid] = bs;
    __syncthreads();
    #pragma unroll
    for (int off = 1; off < PBLK; off <<= 1) {
        int u = (tid >= off) ? sdata[tid - off] : 0;
        __syncthreads();
        sdata[tid] += u;
        __syncthreads();
    }
    const int total  = sdata[PBLK - 1];
    const int before = (bid == 0) ? 0 : sdata[bid - 1];
    __syncthreads();

    // block-local scan of per-thread popcounts
    const int pb = predbits[pt];
    const int ps = __popc(pb);
    sdata[tid] = ps;
    __syncthreads();
    #pragma unroll
    for (int off = 1; off < PBLK; off <<= 1) {
        int u = (tid >= off) ? sdata[tid - off] : 0;
        __syncthreads();
        sdata[tid] += u;
        __syncthreads();
    }
    int r = before + sdata[tid] - ps;

    const int bb = batch[pt];
    const int x = coords[3 * pt], y = coords[3 * pt + 1], z = coords[3 * pt + 2];
    #pragma unroll
    for (int dx = -1; dx <= 1; ++dx)
        #pragma unroll
        for (int dy = -1; dy <= 1; ++dy)
            #pragma unroll
            for (int dz = -1; dz <= 1; ++dz) {
                int k = ((dx + 1) * 3 + (dy + 1)) * 3 + (dz + 1);
                if ((pb >> k) & 1) {
                    int cx = x + dx, cy = y + dy, cz = z + dz;
                    rank_table[cid(bb, cx, cy, cz)] = r;
                    out_key[3 * r + 0] = cx;
                    out_key[3 * r + 1] = cy;
                    out_key[3 * r + 2] = cz;
                    ++r;
                }
            }

    // tail fill out_key rows [total, Tc) with -1
    const int g = bid * PBLK + tid;
    for (int row = total + g; row < Tc; row += NPB * PBLK) {
        out_key[3 * row + 0] = -1;
        out_key[3 * row + 1] = -1;
        out_key[3 * row + 2] = -1;
    }
    if (g == 0) num_out[0] = total;
}

// K5: per point, write in_idx / rel_pos / out_idx (27 each)
__global__ void __launch_bounds__(PBLK)
k5_outputs(const int* __restrict__ coords, const int* __restrict__ batch,
           const int* __restrict__ rank_table,
           int* __restrict__ in_idx, int* __restrict__ out_idx,
           int* __restrict__ rel_pos) {
    const int pt = blockIdx.x * blockDim.x + threadIdx.x;
    if (pt >= NPts) return;
    const int idx = pt & (Nc - 1);
    const int bb  = batch[pt];
    const int x = coords[3 * pt], y = coords[3 * pt + 1], z = coords[3 * pt + 2];
    const int t0 = pt * Kc;
    #pragma unroll
    for (int dx = -1; dx <= 1; ++dx)
        #pragma unroll
        for (int dy = -1; dy <= 1; ++dy)
            #pragma unroll
            for (int dz = -1; dz <= 1; ++dz) {
                int k = ((dx + 1) * 3 + (dy + 1)) * 3 + (dz + 1);
                int t = t0 + k;
                in_idx[t]  = idx;
                rel_pos[t] = k;
                out_idx[t] = rank_table[cid(bb, x + dx, y + dy, z + dz)];
            }
}

extern "C" void kernel_launch(void* const* d_in, const int* in_sizes, int n_in,
                              void* d_out, int out_size, void* d_ws, size_t ws_size,
                              hipStream_t stream) {
    const int* coords = (const int*)d_in[0];   // [B, N, 3]
    const int* batch  = (const int*)d_in[1];   // [B, N]
    int* out = (int*)d_out;
    int* in_idx  = out;                 // [T]
    int* out_idx = out + Tc;            // [T]
    int* rel_pos = out + 2 * Tc;        // [T]
    int* out_key = out + 3 * Tc;        // [T,3]
    int* num_out = out + 6 * Tc;        // [1]

    int* ws = (int*)d_ws;
    int* cell_min   = ws;                       // Bc*P3c = 1,257,728
    int* rank_table = ws + Bc * P3c;            // Bc*P3c
    int* predbits   = ws + 2 * Bc * P3c;        // NPts
    int* blockSums  = predbits + NPts;          // NPB

    k1_init   <<<512, 256, 0, stream>>>(cell_min);
    k2_cellmin<<<NPts / 256, 256, 0, stream>>>(coords, batch, cell_min);
    k3_pred   <<<NPB, PBLK, 0, stream>>>(coords, batch, cell_min,
                                         predbits, blockSums);
    k4_scatter<<<NPB, PBLK, 0, stream>>>(coords, batch, predbits, blockSums,
                                         rank_table, out_key, num_out);
    k5_outputs<<<NPB, PBLK, 0, stream>>>(coords, batch, rank_table,
                                         in_idx, out_idx, rel_pos);
}

// Round 5
// 118.845 us; speedup vs baseline: 1.6122x; 1.0594x over previous
//
#include <hip/hip_runtime.h>

// Problem constants (match reference)
namespace {
constexpr int Bc   = 4;
constexpr int Nc   = 16384;
constexpr int Kc   = 27;
constexpr int Pc   = 68;                    // padded cells per axis: coords -2..65
constexpr int P2c  = Pc * Pc;               // 4624
constexpr int P3c  = Pc * P2c;              // 314432 cells per batch (padded)
constexpr int NPts = Bc * Nc;               // 65536
constexpr int Tc   = NPts * Kc;             // 1,769,472
constexpr int FT   = Bc * P3c;              // 1,257,728 table ints
constexpr int PAD  = 128;                   // guard ints around each table
constexpr int INFv = 0x7fffffff;
}

__device__ __forceinline__ int min3i(int a, int b, int c) {
    return min(min(a, b), c);
}
// cell index: raw coords in [-2, 65]
__device__ __forceinline__ int cid(int bb, int x, int y, int z) {
    return bb * P3c + ((x + 2) * Pc + (y + 2)) * Pc + (z + 2);
}

// K1: init cell_min body + all guard pads to INT_MAX
__global__ void __launch_bounds__(256)
k1_init(int* __restrict__ ws) {
    const int g = blockIdx.x * blockDim.x + threadIdx.x;
    const int stride = gridDim.x * blockDim.x;
    const int4 iv = make_int4(INFv, INFv, INFv, INFv);
    // region 1: pad0 + cell_min + pad1  = PAD+FT+PAD ints
    const int n4 = (PAD + FT + PAD) / 4;
    int4* w4 = reinterpret_cast<int4*>(ws);
    for (int i = g; i < n4; i += stride) w4[i] = iv;
    // region 2: pad2 (after bufA), region 3: pad3 (after bufB)
    if (g < PAD / 4) {
        int4* p2 = reinterpret_cast<int4*>(ws + PAD + FT + PAD + FT);
        p2[g] = iv;
        int4* p3 = reinterpret_cast<int4*>(ws + PAD + FT + PAD + FT + PAD + FT);
        p3[g] = iv;
    }
}

// K2: one atomicMin per point
__global__ void __launch_bounds__(256)
k2_cellmin(const int* __restrict__ coords, const int* __restrict__ batch,
           int* __restrict__ cell_min) {
    const int pt = blockIdx.x * blockDim.x + threadIdx.x;
    const int idx = pt & (Nc - 1);
    const int bb  = batch[pt];
    const int x = coords[3 * pt], y = coords[3 * pt + 1], z = coords[3 * pt + 2];
    atomicMin(&cell_min[cid(bb, x, y, z)], idx);
}

// KZ: sliding min over z (stride 1), coalesced int4
__global__ void __launch_bounds__(256)
kz_pass(const int* __restrict__ cm, int* __restrict__ A) {
    const int i4 = blockIdx.x * blockDim.x + threadIdx.x;
    if (i4 >= FT / 4) return;
    const int4 a = reinterpret_cast<const int4*>(cm)[i4];
    const int am1 = cm[4 * i4 - 1];     // reads guard pad at i4==0
    const int ap4 = cm[4 * i4 + 4];     // reads guard pad at end
    int4 o;
    o.x = min3i(am1, a.x, a.y);
    o.y = min3i(a.x, a.y, a.z);
    o.z = min3i(a.y, a.z, a.w);
    o.w = min3i(a.z, a.w, ap4);
    reinterpret_cast<int4*>(A)[i4] = o;
}

// KY: sliding min over y (stride Pc = 68 ints = 17 int4), coalesced
__global__ void __launch_bounds__(256)
ky_pass(const int* __restrict__ A, int* __restrict__ B) {
    const int i4 = blockIdx.x * blockDim.x + threadIdx.x;
    if (i4 >= FT / 4) return;
    const int4* A4 = reinterpret_cast<const int4*>(A);
    const int4 a = A4[i4 - 17];         // guard pads cover both ends
    const int4 b = A4[i4];
    const int4 c = A4[i4 + 17];
    int4 o;
    o.x = min3i(a.x, b.x, c.x);
    o.y = min3i(a.y, b.y, c.y);
    o.z = min3i(a.z, b.z, c.z);
    o.w = min3i(a.w, b.w, c.w);
    reinterpret_cast<int4*>(B)[i4] = o;
}

// K3: predicate bits. 4 threads per point (j = dy lane, j==3 idle).
//     Thread j loads ymin at 5 x-planes x 3 z for its dy -> 9 bits.
//     OR-combine via LDS; per-block (64 points) popcount sum.
__global__ void __launch_bounds__(256)
k3_pred(const int* __restrict__ coords, const int* __restrict__ batch,
        const int* __restrict__ B,
        int* __restrict__ predbits, int* __restrict__ blockSums) {
    __shared__ int parts[64][4];
    __shared__ int pcnt[64];
    const int tid = threadIdx.x, bid = blockIdx.x;
    const int p = tid >> 2, j = tid & 3;
    const int pt = bid * 64 + p;
    const int idx = pt & (Nc - 1);
    const int bb  = batch[pt];
    const int x = coords[3 * pt], y = coords[3 * pt + 1], z = coords[3 * pt + 2];
    int pb = 0;
    if (j < 3) {
        // table idx: x-planes x..x+4 (cx = x-2..x+2), y row y+j+1 (cy = y+j-1),
        // z cols z+1..z+3 (cz = z-1..z+1)
        const int* base = B + bb * P3c + (x * Pc + (y + j + 1)) * Pc + (z + 1);
        int w[5][3];
        #pragma unroll
        for (int xi = 0; xi < 5; ++xi) {
            const int* q = base + xi * P2c;
            w[xi][0] = q[0]; w[xi][1] = q[1]; w[xi][2] = q[2];
        }
        #pragma unroll
        for (int dx = 0; dx < 3; ++dx)
            #pragma unroll
            for (int dz = 0; dz < 3; ++dz) {
                int m = min3i(w[dx][dz], w[dx + 1][dz], w[dx + 2][dz]);
                pb |= (m == idx) ? (1 << ((dx * 3 + j) * 3 + dz)) : 0;
            }
    }
    parts[p][j] = pb;
    __syncthreads();
    if (j == 0) {
        int full = parts[p][0] | parts[p][1] | parts[p][2];
        predbits[pt] = full;
        pcnt[p] = __popc(full);
    }
    __syncthreads();
    for (int off = 32; off > 0; off >>= 1) {
        if (tid < off) pcnt[tid] += pcnt[tid + off];
        __syncthreads();
    }
    if (tid == 0) blockSums[bid] = pcnt[0];
}

// K4: global rank scan + scatter rank_table / out_key(found rows), num_out
__global__ void __launch_bounds__(256)
k4_scatter(const int* __restrict__ coords, const int* __restrict__ batch,
           const int* __restrict__ predbits, const int* __restrict__ blockSums,
           int* __restrict__ rank_table, int* __restrict__ out_key,
           int* __restrict__ num_out, int* __restrict__ total_ws) {
    __shared__ int sdata[256];
    const int tid = threadIdx.x, bid = blockIdx.x;
    const int pt  = bid * 256 + tid;

    // 1024 blockSums grouped by 4 -> group g == k4 block g's point range
    const int4 bsv = reinterpret_cast<const int4*>(blockSums)[tid];
    int s = bsv.x + bsv.y + bsv.z + bsv.w;
    sdata[tid] = s;
    __syncthreads();
    #pragma unroll
    for (int off = 1; off < 256; off <<= 1) {
        int u = (tid >= off) ? sdata[tid - off] : 0;
        __syncthreads();
        sdata[tid] += u;
        __syncthreads();
    }
    const int total  = sdata[255];
    const int before = (bid == 0) ? 0 : sdata[bid - 1];
    __syncthreads();

    // block-local scan of per-point popcounts
    const int pb = predbits[pt];
    const int ps = __popc(pb);
    sdata[tid] = ps;
    __syncthreads();
    #pragma unroll
    for (int off = 1; off < 256; off <<= 1) {
        int u = (tid >= off) ? sdata[tid - off] : 0;
        __syncthreads();
        sdata[tid] += u;
        __syncthreads();
    }
    int r = before + sdata[tid] - ps;

    const int bb = batch[pt];
    const int x = coords[3 * pt], y = coords[3 * pt + 1], z = coords[3 * pt + 2];
    #pragma unroll
    for (int dx = -1; dx <= 1; ++dx)
        #pragma unroll
        for (int dy = -1; dy <= 1; ++dy)
            #pragma unroll
            for (int dz = -1; dz <= 1; ++dz) {
                int k = ((dx + 1) * 3 + (dy + 1)) * 3 + (dz + 1);
                if ((pb >> k) & 1) {
                    int cx = x + dx, cy = y + dy, cz = z + dz;
                    rank_table[cid(bb, cx, cy, cz)] = r;
                    out_key[3 * r + 0] = cx;
                    out_key[3 * r + 1] = cy;
                    out_key[3 * r + 2] = cz;
                    ++r;
                }
            }
    if (pt == 0) { num_out[0] = total; total_ws[0] = total; }
}

// K5: t-parallel outputs (1.77M threads): in_idx / rel_pos / out_idx,
//     and -1 tail fill of out_key (one row per thread)
__global__ void __launch_bounds__(256)
k5_outputs(const int* __restrict__ coords, const int* __restrict__ batch,
           const int* __restrict__ rank_table, const int* __restrict__ total_ws,
           int* __restrict__ in_idx, int* __restrict__ out_idx,
           int* __restrict__ rel_pos, int* __restrict__ out_key) {
    const int t = blockIdx.x * blockDim.x + threadIdx.x;
    const int pt = t / 27;
    const int k  = t - 27 * pt;
    const int idx = pt & (Nc - 1);
    const int bb  = batch[pt];
    const int x = coords[3 * pt], y = coords[3 * pt + 1], z = coords[3 * pt + 2];
    const int dx = k / 9 - 1;
    const int dy = (k / 3) % 3 - 1;
    const int dz = k - (k / 3) * 3 - 1;
    in_idx[t]  = idx;
    rel_pos[t] = k;
    out_idx[t] = rank_table[cid(bb, x + dx, y + dy, z + dz)];
    if (t >= total_ws[0]) {
        out_key[3 * t + 0] = -1;
        out_key[3 * t + 1] = -1;
        out_key[3 * t + 2] = -1;
    }
}

extern "C" void kernel_launch(void* const* d_in, const int* in_sizes, int n_in,
                              void* d_out, int out_size, void* d_ws, size_t ws_size,
                              hipStream_t stream) {
    const int* coords = (const int*)d_in[0];   // [B, N, 3]
    const int* batch  = (const int*)d_in[1];   // [B, N]
    int* out = (int*)d_out;
    int* in_idx  = out;                 // [T]
    int* out_idx = out + Tc;            // [T]
    int* rel_pos = out + 2 * Tc;        // [T]
    int* out_key = out + 3 * Tc;        // [T,3]
    int* num_out = out + 6 * Tc;        // [1]

    // ws layout: pad0 | cell_min | pad1 | bufA | pad2 | bufB | pad3 |
    //            rank_table | predbits | blockSums | total
    int* ws = (int*)d_ws;
    int* cell_min   = ws + PAD;
    int* bufA       = cell_min + FT + PAD;
    int* bufB       = bufA + FT + PAD;
    int* rank_table = bufB + FT + PAD;
    int* predbits   = rank_table + FT;          // NPts
    int* blockSums  = predbits + NPts;          // 1024
    int* total_ws   = blockSums + 1024;         // 1

    const int pass_blk = (FT / 4 + 255) / 256;  // 1229

    k1_init   <<<1024, 256, 0, stream>>>(ws);
    k2_cellmin<<<NPts / 256, 256, 0, stream>>>(coords, batch, cell_min);
    kz_pass   <<<pass_blk, 256, 0, stream>>>(cell_min, bufA);
    ky_pass   <<<pass_blk, 256, 0, stream>>>(bufA, bufB);
    k3_pred   <<<NPts / 64, 256, 0, stream>>>(coords, batch, bufB,
                                              predbits, blockSums);
    k4_scatter<<<NPts / 256, 256, 0, stream>>>(coords, batch, predbits,
                                               blockSums, rank_table, out_key,
                                               num_out, total_ws);
    k5_outputs<<<Tc / 256, 256, 0, stream>>>(coords, batch, rank_table,
                                             total_ws, in_idx, out_idx,
                                             rel_pos, out_key);
}